// Round 1
// 390.028 us; speedup vs baseline: 1.0889x; 1.0889x over previous
//
#include <hip/hip_runtime.h>

#define NC 24  // N*C = 8*3

typedef float f32x4 __attribute__((ext_vector_type(4)));

// ---------- scalar pyrDown point: 5x5 binomial, reflect-101 ----------
__device__ __forceinline__ float pyr_point(const float* ip, int Hi, int Wi, int oy, int ox)
{
    const float k1[5] = {0.0625f, 0.25f, 0.375f, 0.25f, 0.0625f};
    float acc = 0.f;
#pragma unroll
    for (int i = 0; i < 5; ++i) {
        int y = 2 * oy - 2 + i;
        y = (y < 0) ? -y : y;
        y = (y >= Hi) ? (2 * Hi - 2 - y) : y;
        const float* rp = ip + (size_t)y * Wi;
        float r = 0.f;
#pragma unroll
        for (int j = 0; j < 5; ++j) {
            int xx = 2 * ox - 2 + j;
            xx = (xx < 0) ? -xx : xx;
            xx = (xx >= Wi) ? (2 * Wi - 2 - xx) : xx;
            r = fmaf(k1[j], rp[xx], r);
        }
        acc = fmaf(k1[i], r, acc);
    }
    return acc;
}

// ---------- Gaussian blur point, reflect-101 ----------
template <int K>
__device__ __forceinline__ float blur_point(const float* ip, int H, int W, int oy, int ox,
                                            const float* w)
{
    const int R = K / 2;
    float acc = 0.f;
#pragma unroll
    for (int i = 0; i < K; ++i) {
        int y = oy - R + i;
        y = (y < 0) ? -y : y;
        y = (y >= H) ? (2 * H - 2 - y) : y;
        const float* rp = ip + (size_t)y * W;
        float r = 0.f;
#pragma unroll
        for (int j = 0; j < K; ++j) {
            int xx = ox - R + j;
            xx = (xx < 0) ? -xx : xx;
            xx = (xx >= W) ? (2 * W - 2 - xx) : xx;
            r = fmaf(w[j], rp[xx], r);
        }
        acc = fmaf(w[i], r, acc);
    }
    return acc;
}

// ---------- pyrDown, LDS-staged separable, coalesced loads ----------
// Per block: 64x16 output tile. Stage A: vertical 5-tap at input-x resolution
// (lanes read contiguous x -> coalesced; row reuse via L1) into LDS.
// Stage B: horizontal 5-tap from LDS (stride-2 read = 2-way bank alias = free).
__global__ void __launch_bounds__(256) pyrdown_lds_kernel(
    const float* __restrict__ in, float* __restrict__ out,
    int Hi, int Wi, int Ho, int Wo, float scale, float offs)
{
    const int TW = 132;             // staged input cols: covers 2*64+4 needed
    __shared__ float vs[16 * TW];   // 8448 B
    const int tid = threadIdx.x;
    const int OX = blockIdx.x * 64;
    const int OY = blockIdx.y * 16;
    const int nc = blockIdx.z;
    const float k1[5] = {0.0625f, 0.25f, 0.375f, 0.25f, 0.0625f};
    const float* ip = in + (size_t)nc * Hi * Wi;

    // ---- stage A: vertical conv into LDS ----
    for (int idx = tid; idx < 16 * TW; idx += 256) {
        int r = idx / TW;           // const divisor -> magic-mul
        int c = idx - r * TW;
        int oy = OY + r;
        if (oy >= Ho) oy = Ho - 1;  // partial tile: duplicate row (unused)
        int xc = 2 * OX - 2 + c;    // reflect-101 in x
        xc = (xc < 0) ? -xc : xc;
        xc = (xc >= Wi) ? (2 * Wi - 2 - xc) : xc;
        xc = max(0, min(Wi - 1, xc));  // safety for far-OOB partial tiles
        float acc = 0.f;
#pragma unroll
        for (int i = 0; i < 5; ++i) {
            int y = 2 * oy - 2 + i;  // reflect-101 in y
            y = (y < 0) ? -y : y;
            y = (y >= Hi) ? (2 * Hi - 2 - y) : y;
            acc = fmaf(k1[i], ip[(size_t)y * Wi + xc], acc);
        }
        vs[idx] = acc;
    }
    __syncthreads();

    // ---- stage B: horizontal conv + store (coalesced) ----
    for (int o = tid; o < 1024; o += 256) {
        int r = o >> 6, c = o & 63;
        int ox = OX + c, oy = OY + r;
        if (ox >= Wo || oy >= Ho) continue;
        const float* vp = &vs[r * TW + 2 * c];
        float s = 0.f;
#pragma unroll
        for (int j = 0; j < 5; ++j) s = fmaf(k1[j], vp[j], s);
        out[((size_t)nc * Ho + oy) * Wo + ox] = fmaf(s, scale, offs);
    }
}

// ---------- base_kernel: 80 -> {40,20,10,5} + blurs, all in LDS, 1 block/nc ----------
__global__ void __launch_bounds__(256) base_kernel(
    const float* __restrict__ L4g, float* __restrict__ b30g,
    float* __restrict__ b150g, float* __restrict__ b300g)
{
    __shared__ float sL4[80 * 80];
    __shared__ float sL5[40 * 40];
    __shared__ float sL6[20 * 20];
    __shared__ float sL7[10 * 10];
    __shared__ float sL8[5 * 5];
    const int nc = blockIdx.x;
    const int tid = threadIdx.x;

    float w7[7], w9[9];
    {
        float s = 1.4f, s2 = 2.f * s * s, sum = 0.f;
#pragma unroll
        for (int i = 0; i < 7; ++i) { float d = (float)i - 3.f; w7[i] = expf(-(d * d) / s2); sum += w7[i]; }
#pragma unroll
        for (int i = 0; i < 7; ++i) w7[i] /= sum;
        s = 1.7f; s2 = 2.f * s * s; sum = 0.f;
#pragma unroll
        for (int i = 0; i < 9; ++i) { float d = (float)i - 4.f; w9[i] = expf(-(d * d) / s2); sum += w9[i]; }
#pragma unroll
        for (int i = 0; i < 9; ++i) w9[i] /= sum;
    }

    // coalesced load of L4 (80x80) into LDS
    const float* src = L4g + (size_t)nc * 6400;
    for (int i = tid; i < 1600; i += 256)
        *(f32x4*)&sL4[4 * i] = *(const f32x4*)&src[4 * i];
    __syncthreads();
    for (int i = tid; i < 1600; i += 256) {
        int oy = i / 40, ox = i - oy * 40;
        sL5[i] = pyr_point(sL4, 80, 80, oy, ox);
    }
    __syncthreads();
    for (int i = tid; i < 400; i += 256) {
        int oy = i / 20, ox = i - oy * 20;
        sL6[i] = pyr_point(sL5, 40, 40, oy, ox);
    }
    __syncthreads();
    for (int i = tid; i < 100; i += 256) {
        int oy = i / 10, ox = i - oy * 10;
        sL7[i] = pyr_point(sL6, 20, 20, oy, ox);
    }
    __syncthreads();
    for (int i = tid; i < 25; i += 256) {
        int oy = i / 5, ox = i - oy * 5;
        sL8[i] = pyr_point(sL7, 10, 10, oy, ox);
    }
    __syncthreads();
    for (int i = tid; i < 1600; i += 256) {
        int oy = i / 40, ox = i - oy * 40;
        b30g[(size_t)nc * 1600 + i] = blur_point<7>(sL5, 40, 40, oy, ox, w7);
    }
    for (int i = tid; i < 100; i += 256) {
        int oy = i / 10, ox = i - oy * 10;
        b150g[(size_t)nc * 100 + i] = blur_point<9>(sL7, 10, 10, oy, ox, w9);
    }
    for (int i = tid; i < 25; i += 256) {
        int oy = i / 5, ox = i - oy * 5;
        b300g[(size_t)nc * 25 + i] = blur_point<9>(sL8, 5, 5, oy, ox, w9);
    }
}

// ---------- mega_final: per 64x64 tile, rebuild 9 up-chains in LDS + MSR ----------
// LDS plane offsets (floats), per channel stride 1963:
//   sigma30 : l3(base40)=0, l2=49, l1=130, l0=274        (caps 7,9,12,18)
//   sigma150: l5(base10)=598, l4=634, l3=670, l2=719, l1=800, l0=944
//   sigma300: l6(base5)=1268, l5=1293, l4=1329, l3=1365, l2=1414, l1=1495, l0=1639
__global__ void __launch_bounds__(256) mega_final(
    const float* __restrict__ x,
    const float* __restrict__ b30g,
    const float* __restrict__ b150g,
    const float* __restrict__ b300g,
    float* __restrict__ out)
{
    const int H = 1280, W = 1280;
    __shared__ float S[3 * 1963];

    const int tid = threadIdx.x;
    const int X0 = blockIdx.x * 64, Y0 = blockIdx.y * 64;
    const int n = blockIdx.z;

    // per-level needed ranges (same for all chains); l: 0=320,1=160,2=80,3=40,4=20,5=10,6=5
    const int LS[7] = {320, 160, 80, 40, 20, 10, 5};
    int ay[7], by[7], ax[7], bx[7];
    ay[0] = max(0, Y0 / 4 - 1); by[0] = min(319, Y0 / 4 + 16);
    ax[0] = max(0, X0 / 4 - 1); bx[0] = min(319, X0 / 4 + 16);
#pragma unroll
    for (int l = 1; l < 7; ++l) {
        ay[l] = max(0, (ay[l - 1] >> 1) - 1); by[l] = min(LS[l] - 1, (by[l - 1] >> 1) + 1);
        ax[l] = max(0, (ax[l - 1] >> 1) - 1); bx[l] = min(LS[l] - 1, (bx[l - 1] >> 1) + 1);
    }
    const int o300t[7] = {1639, 1495, 1414, 1365, 1329, 1293, 1268};
    const int o150t[6] = {944, 800, 719, 670, 634, 598};
    const int o30t[4]  = {274, 130, 49, 0};

    // ---- stage 0: load base patches ----
    {
        int ny = by[3] - ay[3] + 1, nx = bx[3] - ax[3] + 1;  // b30 at l3
        for (int i = tid; i < 3 * ny * nx; i += 256) {
            int c = i / (ny * nx), pt = i - c * (ny * nx);
            int ry = pt / nx, rx = pt - ry * nx;
            S[c * 1963 + o30t[3] + pt] =
                b30g[(size_t)(n * 3 + c) * 1600 + (ay[3] + ry) * 40 + ax[3] + rx];
        }
        ny = by[5] - ay[5] + 1; nx = bx[5] - ax[5] + 1;      // b150 at l5
        for (int i = tid; i < 3 * ny * nx; i += 256) {
            int c = i / (ny * nx), pt = i - c * (ny * nx);
            int ry = pt / nx, rx = pt - ry * nx;
            S[c * 1963 + o150t[5] + pt] =
                b150g[(size_t)(n * 3 + c) * 100 + (ay[5] + ry) * 10 + ax[5] + rx];
        }
        ny = by[6] - ay[6] + 1; nx = bx[6] - ax[6] + 1;      // b300 at l6
        for (int i = tid; i < 3 * ny * nx; i += 256) {
            int c = i / (ny * nx), pt = i - c * (ny * nx);
            int ry = pt / nx, rx = pt - ry * nx;
            S[c * 1963 + o300t[6] + pt] =
                b300g[(size_t)(n * 3 + c) * 25 + (ay[6] + ry) * 5 + ax[6] + rx];
        }
    }
    __syncthreads();

    // ---- up ladder: l = 5..0 (dst level l, src level l+1) ----
#pragma unroll
    for (int l = 5; l >= 0; --l) {
        int srcO[9], dstO[9];
        int m = 0;
#pragma unroll
        for (int c = 0; c < 3; ++c) { srcO[m] = c * 1963 + o300t[l + 1]; dstO[m] = c * 1963 + o300t[l]; ++m; }
        if (l <= 4) {
#pragma unroll
            for (int c = 0; c < 3; ++c) { srcO[m] = c * 1963 + o150t[l + 1]; dstO[m] = c * 1963 + o150t[l]; ++m; }
        }
        if (l <= 2) {
#pragma unroll
            for (int c = 0; c < 3; ++c) { srcO[m] = c * 1963 + o30t[l + 1]; dstO[m] = c * 1963 + o30t[l]; ++m; }
        }
        int ny = by[l] - ay[l] + 1, nx = bx[l] - ax[l] + 1;
        int nxS = bx[l + 1] - ax[l + 1] + 1;
        int Ssrc = LS[l + 1];
        int npts = ny * nx;
        for (int i = tid; i < m * npts; i += 256) {
            int p = i / npts, pt = i - p * npts;
            int ry = pt / nx, rx = pt - ry * nx;
            int oy = ay[l] + ry, ox = ax[l] + rx;
            int my = oy >> 1, py = oy & 1;
            int mx = ox >> 1, px = ox & 1;
            int yA = py ? my : max(my - 1, 0);
            int yB = py ? min(my + 1, Ssrc - 1) : my;
            float wyA = py ? 0.75f : 0.25f, wyB = py ? 0.25f : 0.75f;
            int xA = px ? mx : max(mx - 1, 0);
            int xB = px ? min(mx + 1, Ssrc - 1) : mx;
            float wxA = px ? 0.75f : 0.25f, wxB = px ? 0.25f : 0.75f;
            const float* sp = &S[srcO[p]];
            int la = (yA - ay[l + 1]) * nxS - ax[l + 1];
            int lb = (yB - ay[l + 1]) * nxS - ax[l + 1];
            float v = wyA * (wxA * sp[la + xA] + wxB * sp[la + xB]) +
                      wyB * (wxA * sp[lb + xA] + wxB * sp[lb + xB]);
            S[dstO[p] + pt] = v;
        }
        __syncthreads();
    }

    // ---- MSR per thread: 4x4 px block, 3 channels ----
    int tyi = tid >> 4, txi = tid & 15;
    int byi = Y0 / 4 + tyi, bxi = X0 / 4 + txi;   // global 320-level index
    int nx0 = bx[0] - ax[0] + 1;
    int ry[3], rx[3];
    ry[0] = (byi > 0 ? byi - 1 : 0) - ay[0]; ry[1] = byi - ay[0];
    ry[2] = (byi < 319 ? byi + 1 : 319) - ay[0];
    rx[0] = (bxi > 0 ? bxi - 1 : 0) - ax[0]; rx[1] = bxi - ax[0];
    rx[2] = (bxi < 319 ? bxi + 1 : 319) - ax[0];
    const int ol0[3] = {274, 944, 1639};  // sigma30/150/300 at l0

    f32x4 xi[3][4];
#pragma unroll
    for (int c = 0; c < 3; ++c)
#pragma unroll
        for (int qy = 0; qy < 4; ++qy)
            xi[c][qy] = __builtin_nontemporal_load(
                (const f32x4*)&x[((size_t)(n * 3 + c) * H + 4 * byi + qy) * W + 4 * bxi]);

    float crcp[4][4];
#pragma unroll
    for (int qy = 0; qy < 4; ++qy)
#pragma unroll
        for (int qx = 0; qx < 4; ++qx) {
            float s = (xi[0][qy][qx] + xi[1][qy][qx] + xi[2][qy][qx]) * 255.f + 3.f;
            crcp[qy][qx] = __fdividef(2.f, s + 1e-6f);
        }

#pragma unroll
    for (int c = 0; c < 3; ++c) {
        float prod[4][4];
#pragma unroll
        for (int qy = 0; qy < 4; ++qy)
#pragma unroll
            for (int qx = 0; qx < 4; ++qx) prod[qy][qx] = 1.f;

#pragma unroll
        for (int s = 0; s < 3; ++s) {
            const float* fp = &S[c * 1963 + ol0[s]];
            float v[3][3];
#pragma unroll
            for (int i = 0; i < 3; ++i)
#pragma unroll
                for (int j = 0; j < 3; ++j) v[i][j] = fp[ry[i] * nx0 + rx[j]];
            // 4x upsample weights: rows {0.375,0.625,0},{0.1875,0.75,0.0625},
            // {0.0625,0.75,0.1875},{0,0.625,0.375} — zero taps pruned
            // (fmaf(0,v,acc)==acc, so this is numerically equivalent).
            float cy[4][3];
#pragma unroll
            for (int j = 0; j < 3; ++j) {
                float v0 = v[0][j], v1 = v[1][j], v2 = v[2][j];
                cy[0][j] = fmaf(0.375f, v0, 0.625f * v1);
                cy[1][j] = fmaf(0.1875f, v0, fmaf(0.75f, v1, 0.0625f * v2));
                cy[2][j] = fmaf(0.0625f, v0, fmaf(0.75f, v1, 0.1875f * v2));
                cy[3][j] = fmaf(0.625f, v1, 0.375f * v2);
            }
#pragma unroll
            for (int qy = 0; qy < 4; ++qy) {
                float a0 = cy[qy][0], a1 = cy[qy][1], a2 = cy[qy][2];
                float t0 = fmaf(0.375f, a0, 0.625f * a1);
                float t1 = fmaf(0.1875f, a0, fmaf(0.75f, a1, 0.0625f * a2));
                float t2 = fmaf(0.0625f, a0, fmaf(0.75f, a1, 0.1875f * a2));
                float t3 = fmaf(0.625f, a1, 0.375f * a2);
                prod[qy][0] *= (t0 + 1e-6f);
                prod[qy][1] *= (t1 + 1e-6f);
                prod[qy][2] *= (t2 + 1e-6f);
                prod[qy][3] *= (t3 + 1e-6f);
            }
        }

#pragma unroll
        for (int qy = 0; qy < 4; ++qy) {
            f32x4 o;
#pragma unroll
            for (int qx = 0; qx < 4; ++qx) {
                float img = xi[c][qy][qx] * 255.f + 1.f;
                float a = img + 1e-6f;
                float l2a = __log2f(__fdividef(a * a * a, prod[qy][qx]));
                float carg = fmaf(img, crcp[qy][qx], 1.f);
                float l2c = __log2f(carg);
                float e = fmaf(l2a * l2c, 81.55715246f, 128.f);
                e = fminf(fmaxf(e, 0.f), 255.f);
                o[qx] = e * (1.f / 255.f);
            }
            __builtin_nontemporal_store(
                o, (f32x4*)&out[((size_t)(n * 3 + c) * H + 4 * byi + qy) * W + 4 * bxi]);
        }
    }
}

extern "C" void kernel_launch(void* const* d_in, const int* in_sizes, int n_in,
                              void* d_out, int out_size, void* d_ws, size_t ws_size,
                              hipStream_t stream)
{
    const float* x = (const float*)d_in[0];
    float* out = (float*)d_out;
    float* ws = (float*)d_ws;

    size_t off = 0;
    auto alloc = [&](int d) { float* p = ws + off; off += (size_t)NC * d * d; return p; };
    float* L1 = alloc(640);
    float* L2 = alloc(320);
    float* L3 = alloc(160);
    float* L4 = alloc(80);
    float* b30 = alloc(40);
    float* b150 = alloc(10);
    float* b300 = alloc(5);
    (void)ws_size; (void)in_sizes; (void)n_in; (void)out_size;

    dim3 blk(256, 1, 1);
    auto gridP = [&](int Wo, int Ho) { return dim3((Wo + 63) / 64, (Ho + 15) / 16, NC); };

    pyrdown_lds_kernel<<<gridP(640, 640), blk, 0, stream>>>(x,  L1, 1280, 1280, 640, 640, 255.f, 1.f);
    pyrdown_lds_kernel<<<gridP(320, 320), blk, 0, stream>>>(L1, L2, 640, 640, 320, 320, 1.f, 0.f);
    pyrdown_lds_kernel<<<gridP(160, 160), blk, 0, stream>>>(L2, L3, 320, 320, 160, 160, 1.f, 0.f);
    pyrdown_lds_kernel<<<gridP(80,  80),  blk, 0, stream>>>(L3, L4, 160, 160, 80, 80, 1.f, 0.f);
    base_kernel<<<dim3(NC, 1, 1), dim3(256, 1, 1), 0, stream>>>(L4, b30, b150, b300);
    mega_final<<<dim3(20, 20, 8), dim3(256, 1, 1), 0, stream>>>(x, b30, b150, b300, out);
}

// Round 2
// 356.175 us; speedup vs baseline: 1.1924x; 1.0950x over previous
//
#include <hip/hip_runtime.h>

#define NC 24  // N*C = 8*3

typedef float f32x4 __attribute__((ext_vector_type(4)));

// ---------- scalar pyrDown point: 5x5 binomial, reflect-101 ----------
__device__ __forceinline__ float pyr_point(const float* ip, int Hi, int Wi, int oy, int ox)
{
    const float k1[5] = {0.0625f, 0.25f, 0.375f, 0.25f, 0.0625f};
    float acc = 0.f;
#pragma unroll
    for (int i = 0; i < 5; ++i) {
        int y = 2 * oy - 2 + i;
        y = (y < 0) ? -y : y;
        y = (y >= Hi) ? (2 * Hi - 2 - y) : y;
        const float* rp = ip + (size_t)y * Wi;
        float r = 0.f;
#pragma unroll
        for (int j = 0; j < 5; ++j) {
            int xx = 2 * ox - 2 + j;
            xx = (xx < 0) ? -xx : xx;
            xx = (xx >= Wi) ? (2 * Wi - 2 - xx) : xx;
            r = fmaf(k1[j], rp[xx], r);
        }
        acc = fmaf(k1[i], r, acc);
    }
    return acc;
}

// ---------- Gaussian blur point, reflect-101 ----------
template <int K>
__device__ __forceinline__ float blur_point(const float* ip, int H, int W, int oy, int ox,
                                            const float* w)
{
    const int R = K / 2;
    float acc = 0.f;
#pragma unroll
    for (int i = 0; i < K; ++i) {
        int y = oy - R + i;
        y = (y < 0) ? -y : y;
        y = (y >= H) ? (2 * H - 2 - y) : y;
        const float* rp = ip + (size_t)y * W;
        float r = 0.f;
#pragma unroll
        for (int j = 0; j < K; ++j) {
            int xx = ox - R + j;
            xx = (xx < 0) ? -xx : xx;
            xx = (xx >= W) ? (2 * W - 2 - xx) : xx;
            r = fmaf(w[j], rp[xx], r);
        }
        acc = fmaf(w[i], r, acc);
    }
    return acc;
}

// ---------- pyrDown, LDS-staged separable, coalesced loads ----------
__global__ void __launch_bounds__(256) pyrdown_lds_kernel(
    const float* __restrict__ in, float* __restrict__ out,
    int Hi, int Wi, int Ho, int Wo, float scale, float offs)
{
    const int TW = 132;             // staged input cols: covers 2*64+4 needed
    __shared__ float vs[16 * TW];   // 8448 B
    const int tid = threadIdx.x;
    const int OX = blockIdx.x * 64;
    const int OY = blockIdx.y * 16;
    const int nc = blockIdx.z;
    const float k1[5] = {0.0625f, 0.25f, 0.375f, 0.25f, 0.0625f};
    const float* ip = in + (size_t)nc * Hi * Wi;

    // ---- stage A: vertical conv into LDS ----
    for (int idx = tid; idx < 16 * TW; idx += 256) {
        int r = idx / TW;
        int c = idx - r * TW;
        int oy = OY + r;
        if (oy >= Ho) oy = Ho - 1;
        int xc = 2 * OX - 2 + c;    // reflect-101 in x
        xc = (xc < 0) ? -xc : xc;
        xc = (xc >= Wi) ? (2 * Wi - 2 - xc) : xc;
        xc = max(0, min(Wi - 1, xc));
        float acc = 0.f;
#pragma unroll
        for (int i = 0; i < 5; ++i) {
            int y = 2 * oy - 2 + i;  // reflect-101 in y
            y = (y < 0) ? -y : y;
            y = (y >= Hi) ? (2 * Hi - 2 - y) : y;
            acc = fmaf(k1[i], ip[(size_t)y * Wi + xc], acc);
        }
        vs[idx] = acc;
    }
    __syncthreads();

    // ---- stage B: horizontal conv + store (coalesced) ----
    for (int o = tid; o < 1024; o += 256) {
        int r = o >> 6, c = o & 63;
        int ox = OX + c, oy = OY + r;
        if (ox >= Wo || oy >= Ho) continue;
        const float* vp = &vs[r * TW + 2 * c];
        float s = 0.f;
#pragma unroll
        for (int j = 0; j < 5; ++j) s = fmaf(k1[j], vp[j], s);
        out[((size_t)nc * Ho + oy) * Wo + ox] = fmaf(s, scale, offs);
    }
}

// ---------- base_kernel: 80 -> {40,20,10,5} + blurs, all in LDS, 1 block/nc ----------
__global__ void __launch_bounds__(256) base_kernel(
    const float* __restrict__ L4g, float* __restrict__ b30g,
    float* __restrict__ b150g, float* __restrict__ b300g)
{
    __shared__ float sL4[80 * 80];
    __shared__ float sL5[40 * 40];
    __shared__ float sL6[20 * 20];
    __shared__ float sL7[10 * 10];
    __shared__ float sL8[5 * 5];
    const int nc = blockIdx.x;
    const int tid = threadIdx.x;

    float w7[7], w9[9];
    {
        float s = 1.4f, s2 = 2.f * s * s, sum = 0.f;
#pragma unroll
        for (int i = 0; i < 7; ++i) { float d = (float)i - 3.f; w7[i] = expf(-(d * d) / s2); sum += w7[i]; }
#pragma unroll
        for (int i = 0; i < 7; ++i) w7[i] /= sum;
        s = 1.7f; s2 = 2.f * s * s; sum = 0.f;
#pragma unroll
        for (int i = 0; i < 9; ++i) { float d = (float)i - 4.f; w9[i] = expf(-(d * d) / s2); sum += w9[i]; }
#pragma unroll
        for (int i = 0; i < 9; ++i) w9[i] /= sum;
    }

    const float* src = L4g + (size_t)nc * 6400;
    for (int i = tid; i < 1600; i += 256)
        *(f32x4*)&sL4[4 * i] = *(const f32x4*)&src[4 * i];
    __syncthreads();
    for (int i = tid; i < 1600; i += 256) {
        int oy = i / 40, ox = i - oy * 40;
        sL5[i] = pyr_point(sL4, 80, 80, oy, ox);
    }
    __syncthreads();
    for (int i = tid; i < 400; i += 256) {
        int oy = i / 20, ox = i - oy * 20;
        sL6[i] = pyr_point(sL5, 40, 40, oy, ox);
    }
    __syncthreads();
    for (int i = tid; i < 100; i += 256) {
        int oy = i / 10, ox = i - oy * 10;
        sL7[i] = pyr_point(sL6, 20, 20, oy, ox);
    }
    __syncthreads();
    for (int i = tid; i < 25; i += 256) {
        int oy = i / 5, ox = i - oy * 5;
        sL8[i] = pyr_point(sL7, 10, 10, oy, ox);
    }
    __syncthreads();
    for (int i = tid; i < 1600; i += 256) {
        int oy = i / 40, ox = i - oy * 40;
        b30g[(size_t)nc * 1600 + i] = blur_point<7>(sL5, 40, 40, oy, ox, w7);
    }
    for (int i = tid; i < 100; i += 256) {
        int oy = i / 10, ox = i - oy * 10;
        b150g[(size_t)nc * 100 + i] = blur_point<9>(sL7, 10, 10, oy, ox, w9);
    }
    for (int i = tid; i < 25; i += 256) {
        int oy = i / 5, ox = i - oy * 5;
        b300g[(size_t)nc * 25 + i] = blur_point<9>(sL8, 5, 5, oy, ox, w9);
    }
}

// ======================= mega_final (restructured) =======================
// Nominal (unclamped) patch ranges with COMPILE-TIME sizes.
// a0 = 16*b - 1 (always odd); a_{l+1} = (a_l>>1) - 1.
// Patch sizes per level (exact, derived from parity): {18,12,8,6,5,5,5}.
// Patch entry i stores the level value at clamp(a_l + i, 0, LS_l-1); all
// reads use nominal indexing -> identical results to clamped-range scheme.
// Per-channel LDS layout (floats), CH = 1721:
//   s30 : l3=0(36)   l2=36(64)   l1=100(144)  l0=244(324)
//   s150: l5=568(25) l4=593(25)  l3=618(36)   l2=654(64)  l1=718(144) l0=862(324)
//   s300: l6=1186(25) l5=1211(25) l4=1236(25) l3=1261(36) l2=1297(64) l1=1333(144) l0=1397(324)
#define CH 1721
#define O30_3 0
#define O30_2 36
#define O30_1 100
#define O30_0 244
#define O150_5 568
#define O150_4 593
#define O150_3 618
#define O150_2 654
#define O150_1 718
#define O150_0 862
#define O300_6 1186
#define O300_5 1211
#define O300_4 1236
#define O300_3 1261
#define O300_2 1297
#define O300_1 1333
#define O300_0 1397

// One 2x-bilinear upsample level: NPL planes, dst patch ND x ND (level size LSD),
// src patch NS x NS (level size LSD/2). Geometry computed ONCE per point and
// shared across all planes; all divisors/offsets compile-time.
template <int NPL, int ND, int NS, int LSD>
__device__ __forceinline__ void up_level(float* __restrict__ S,
                                         const int (&srcO)[NPL], const int (&dstO)[NPL],
                                         int ayD, int axD, int ayS, int axS)
{
    const int SSRC = LSD / 2;
    const int NPTS = ND * ND;
    for (int pt = threadIdx.x; pt < NPTS; pt += 256) {
        int ry = pt / ND, rx = pt - ry * ND;           // const divisor -> magic mul
        int gy = min(max(ayD + ry, 0), LSD - 1);
        int gx = min(max(axD + rx, 0), LSD - 1);
        int my = gy >> 1, py = gy & 1;
        int mx = gx >> 1, px = gx & 1;
        int yA = py ? my : max(my - 1, 0);
        int yB = py ? min(my + 1, SSRC - 1) : my;
        float wyA = py ? 0.75f : 0.25f;
        float wyB = 1.0f - wyA;
        int xA = px ? mx : max(mx - 1, 0);
        int xB = px ? min(mx + 1, SSRC - 1) : mx;
        float wxA = px ? 0.75f : 0.25f;
        float wxB = 1.0f - wxA;
        int la = (yA - ayS) * NS + (xA - axS);
        int laB = la + (xB - xA);
        int lb = (yB - ayS) * NS + (xA - axS);
        int lbB = lb + (xB - xA);
#pragma unroll
        for (int p = 0; p < NPL; ++p) {                // compile-time plane offsets
            const float* sp = S + srcO[p];
            float v = wyA * fmaf(wxA, sp[la], wxB * sp[laB]) +
                      wyB * fmaf(wxA, sp[lb], wxB * sp[lbB]);
            S[dstO[p] + pt] = v;
        }
    }
}

__global__ void __launch_bounds__(256) mega_final(
    const float* __restrict__ x,
    const float* __restrict__ b30g,
    const float* __restrict__ b150g,
    const float* __restrict__ b300g,
    float* __restrict__ out)
{
    const int H = 1280, W = 1280;
    __shared__ float S[3 * CH];

    const int tid = threadIdx.x;
    const int X0 = blockIdx.x * 64, Y0 = blockIdx.y * 64;
    const int n = blockIdx.z;

    // nominal patch starts
    int ay[7], ax[7];
    ay[0] = (Y0 >> 2) - 1;  // 16*by - 1 (odd)
    ax[0] = (X0 >> 2) - 1;
#pragma unroll
    for (int l = 1; l < 7; ++l) {
        ay[l] = (ay[l - 1] >> 1) - 1;
        ax[l] = (ax[l - 1] >> 1) - 1;
    }

    // ---- stage 0: load base patches (disjoint thread ranges, no divergence cost) ----
    if (tid < 36) {                       // b30 at l3: 6x6
        int ry = tid / 6, rx = tid - ry * 6;
        int gy = min(max(ay[3] + ry, 0), 39);
        int gx = min(max(ax[3] + rx, 0), 39);
#pragma unroll
        for (int c = 0; c < 3; ++c)
            S[c * CH + O30_3 + tid] = b30g[(size_t)(n * 3 + c) * 1600 + gy * 40 + gx];
    } else if (tid >= 64 && tid < 89) {   // b150 at l5: 5x5
        int t = tid - 64;
        int ry = t / 5, rx = t - ry * 5;
        int gy = min(max(ay[5] + ry, 0), 9);
        int gx = min(max(ax[5] + rx, 0), 9);
#pragma unroll
        for (int c = 0; c < 3; ++c)
            S[c * CH + O150_5 + t] = b150g[(size_t)(n * 3 + c) * 100 + gy * 10 + gx];
    } else if (tid >= 128 && tid < 153) { // b300 at l6: 5x5
        int t = tid - 128;
        int ry = t / 5, rx = t - ry * 5;
        int gy = min(max(ay[6] + ry, 0), 4);
        int gx = min(max(ax[6] + rx, 0), 4);
#pragma unroll
        for (int c = 0; c < 3; ++c)
            S[c * CH + O300_6 + t] = b300g[(size_t)(n * 3 + c) * 25 + gy * 5 + gx];
    }
    __syncthreads();

    // ---- up ladder (all offsets compile-time) ----
    {
        const int s[3] = {O300_6, O300_6 + CH, O300_6 + 2 * CH};
        const int d[3] = {O300_5, O300_5 + CH, O300_5 + 2 * CH};
        up_level<3, 5, 5, 10>(S, s, d, ay[5], ax[5], ay[6], ax[6]);
    }
    __syncthreads();
    {
        const int s[6] = {O300_5, O300_5 + CH, O300_5 + 2 * CH, O150_5, O150_5 + CH, O150_5 + 2 * CH};
        const int d[6] = {O300_4, O300_4 + CH, O300_4 + 2 * CH, O150_4, O150_4 + CH, O150_4 + 2 * CH};
        up_level<6, 5, 5, 20>(S, s, d, ay[4], ax[4], ay[5], ax[5]);
    }
    __syncthreads();
    {
        const int s[6] = {O300_4, O300_4 + CH, O300_4 + 2 * CH, O150_4, O150_4 + CH, O150_4 + 2 * CH};
        const int d[6] = {O300_3, O300_3 + CH, O300_3 + 2 * CH, O150_3, O150_3 + CH, O150_3 + 2 * CH};
        up_level<6, 6, 5, 40>(S, s, d, ay[3], ax[3], ay[4], ax[4]);
    }
    __syncthreads();
    {
        const int s[9] = {O300_3, O300_3 + CH, O300_3 + 2 * CH, O150_3, O150_3 + CH, O150_3 + 2 * CH,
                          O30_3, O30_3 + CH, O30_3 + 2 * CH};
        const int d[9] = {O300_2, O300_2 + CH, O300_2 + 2 * CH, O150_2, O150_2 + CH, O150_2 + 2 * CH,
                          O30_2, O30_2 + CH, O30_2 + 2 * CH};
        up_level<9, 8, 6, 80>(S, s, d, ay[2], ax[2], ay[3], ax[3]);
    }
    __syncthreads();
    {
        const int s[9] = {O300_2, O300_2 + CH, O300_2 + 2 * CH, O150_2, O150_2 + CH, O150_2 + 2 * CH,
                          O30_2, O30_2 + CH, O30_2 + 2 * CH};
        const int d[9] = {O300_1, O300_1 + CH, O300_1 + 2 * CH, O150_1, O150_1 + CH, O150_1 + 2 * CH,
                          O30_1, O30_1 + CH, O30_1 + 2 * CH};
        up_level<9, 12, 8, 160>(S, s, d, ay[1], ax[1], ay[2], ax[2]);
    }
    __syncthreads();
    {
        const int s[9] = {O300_1, O300_1 + CH, O300_1 + 2 * CH, O150_1, O150_1 + CH, O150_1 + 2 * CH,
                          O30_1, O30_1 + CH, O30_1 + 2 * CH};
        const int d[9] = {O300_0, O300_0 + CH, O300_0 + 2 * CH, O150_0, O150_0 + CH, O150_0 + 2 * CH,
                          O30_0, O30_0 + CH, O30_0 + 2 * CH};
        up_level<9, 18, 12, 320>(S, s, d, ay[0], ax[0], ay[1], ax[1]);
    }
    __syncthreads();

    // ---- MSR per thread: 4x4 px block, 3 channels ----
    int tyi = tid >> 4, txi = tid & 15;
    int byi = (Y0 >> 2) + tyi, bxi = (X0 >> 2) + txi;   // global 320-level index
    int ry[3], rx[3];
    ry[0] = max(byi - 1, 0) - ay[0]; ry[1] = byi - ay[0]; ry[2] = min(byi + 1, 319) - ay[0];
    rx[0] = max(bxi - 1, 0) - ax[0]; rx[1] = bxi - ax[0]; rx[2] = min(bxi + 1, 319) - ax[0];
    const int ol0[3] = {O30_0, O150_0, O300_0};

    f32x4 xi[3][4];
#pragma unroll
    for (int c = 0; c < 3; ++c)
#pragma unroll
        for (int qy = 0; qy < 4; ++qy)
            xi[c][qy] = __builtin_nontemporal_load(
                (const f32x4*)&x[((size_t)(n * 3 + c) * H + 4 * byi + qy) * W + 4 * bxi]);

    float crcp[4][4];
#pragma unroll
    for (int qy = 0; qy < 4; ++qy)
#pragma unroll
        for (int qx = 0; qx < 4; ++qx) {
            float s = (xi[0][qy][qx] + xi[1][qy][qx] + xi[2][qy][qx]) * 255.f + 3.f;
            crcp[qy][qx] = __fdividef(2.f, s + 1e-6f);
        }

#pragma unroll
    for (int c = 0; c < 3; ++c) {
        float prod[4][4];
#pragma unroll
        for (int qy = 0; qy < 4; ++qy)
#pragma unroll
            for (int qx = 0; qx < 4; ++qx) prod[qy][qx] = 1.f;

#pragma unroll
        for (int s = 0; s < 3; ++s) {
            const float* fp = &S[c * CH + ol0[s]];
            float v[3][3];
#pragma unroll
            for (int i = 0; i < 3; ++i)
#pragma unroll
                for (int j = 0; j < 3; ++j) v[i][j] = fp[ry[i] * 18 + rx[j]];
            // 4x upsample weights (composition of two 2x bilinears), zero taps pruned
            float cy[4][3];
#pragma unroll
            for (int j = 0; j < 3; ++j) {
                float v0 = v[0][j], v1 = v[1][j], v2 = v[2][j];
                cy[0][j] = fmaf(0.375f, v0, 0.625f * v1);
                cy[1][j] = fmaf(0.1875f, v0, fmaf(0.75f, v1, 0.0625f * v2));
                cy[2][j] = fmaf(0.0625f, v0, fmaf(0.75f, v1, 0.1875f * v2));
                cy[3][j] = fmaf(0.625f, v1, 0.375f * v2);
            }
#pragma unroll
            for (int qy = 0; qy < 4; ++qy) {
                float a0 = cy[qy][0], a1 = cy[qy][1], a2 = cy[qy][2];
                float t0 = fmaf(0.375f, a0, 0.625f * a1);
                float t1 = fmaf(0.1875f, a0, fmaf(0.75f, a1, 0.0625f * a2));
                float t2 = fmaf(0.0625f, a0, fmaf(0.75f, a1, 0.1875f * a2));
                float t3 = fmaf(0.625f, a1, 0.375f * a2);
                prod[qy][0] *= (t0 + 1e-6f);
                prod[qy][1] *= (t1 + 1e-6f);
                prod[qy][2] *= (t2 + 1e-6f);
                prod[qy][3] *= (t3 + 1e-6f);
            }
        }

#pragma unroll
        for (int qy = 0; qy < 4; ++qy) {
            f32x4 o;
#pragma unroll
            for (int qx = 0; qx < 4; ++qx) {
                float img = xi[c][qy][qx] * 255.f + 1.f;
                float a = img + 1e-6f;
                float l2a = __log2f(__fdividef(a * a * a, prod[qy][qx]));
                float carg = fmaf(img, crcp[qy][qx], 1.f);
                float l2c = __log2f(carg);
                float e = fmaf(l2a * l2c, 81.55715246f, 128.f);
                e = fminf(fmaxf(e, 0.f), 255.f);
                o[qx] = e * (1.f / 255.f);
            }
            __builtin_nontemporal_store(
                o, (f32x4*)&out[((size_t)(n * 3 + c) * H + 4 * byi + qy) * W + 4 * bxi]);
        }
    }
}

extern "C" void kernel_launch(void* const* d_in, const int* in_sizes, int n_in,
                              void* d_out, int out_size, void* d_ws, size_t ws_size,
                              hipStream_t stream)
{
    const float* x = (const float*)d_in[0];
    float* out = (float*)d_out;
    float* ws = (float*)d_ws;

    size_t off = 0;
    auto alloc = [&](int d) { float* p = ws + off; off += (size_t)NC * d * d; return p; };
    float* L1 = alloc(640);
    float* L2 = alloc(320);
    float* L3 = alloc(160);
    float* L4 = alloc(80);
    float* b30 = alloc(40);
    float* b150 = alloc(10);
    float* b300 = alloc(5);
    (void)ws_size; (void)in_sizes; (void)n_in; (void)out_size;

    dim3 blk(256, 1, 1);
    auto gridP = [&](int Wo, int Ho) { return dim3((Wo + 63) / 64, (Ho + 15) / 16, NC); };

    pyrdown_lds_kernel<<<gridP(640, 640), blk, 0, stream>>>(x,  L1, 1280, 1280, 640, 640, 255.f, 1.f);
    pyrdown_lds_kernel<<<gridP(320, 320), blk, 0, stream>>>(L1, L2, 640, 640, 320, 320, 1.f, 0.f);
    pyrdown_lds_kernel<<<gridP(160, 160), blk, 0, stream>>>(L2, L3, 320, 320, 160, 160, 1.f, 0.f);
    pyrdown_lds_kernel<<<gridP(80,  80),  blk, 0, stream>>>(L3, L4, 160, 160, 80, 80, 1.f, 0.f);
    base_kernel<<<dim3(NC, 1, 1), dim3(256, 1, 1), 0, stream>>>(L4, b30, b150, b300);
    mega_final<<<dim3(20, 20, 8), dim3(256, 1, 1), 0, stream>>>(x, b30, b150, b300, out);
}